// Round 1
// baseline (886.095 us; speedup 1.0000x reference)
//
#include <hip/hip_runtime.h>

#define HH 512
#define WW 512
#define NPIX (HH * WW)
#define NPROP 30
#define MAXC 32768

// ---------------- Kernel 1: center_raw = mean over batch of channel 17 ----------------
__global__ void k_center_raw(const float* __restrict__ pred, float* __restrict__ craw,
                             unsigned int* __restrict__ counter) {
    int i = blockIdx.x * blockDim.x + threadIdx.x;
    if (i == 0) *counter = 0u;  // reset candidate counter each call (ws not re-poisoned)
    if (i < NPIX) {
        float a = pred[17 * NPIX + i];            // batch 0, channel 17
        float b = pred[(18 + 17) * NPIX + i];     // batch 1, channel 17
        craw[i] = 0.5f * (a + b);
    }
}

// ---------------- Kernel 2: center2 = (craw + avgpool3(craw)) / 2 ----------------
// avg_pool2d count_include_pad=True: zero-pad, always divide by 9.
__global__ void k_center2(const float* __restrict__ craw, float* __restrict__ c2) {
    int i = blockIdx.x * blockDim.x + threadIdx.x;
    if (i >= NPIX) return;
    int x = i & (WW - 1);
    int y = i >> 9;
    float s = 0.0f;
    #pragma unroll
    for (int dy = -1; dy <= 1; ++dy) {
        int yy = y + dy;
        if (yy < 0 || yy >= HH) continue;
        #pragma unroll
        for (int dx = -1; dx <= 1; ++dx) {
            int xx = x + dx;
            if (xx < 0 || xx >= WW) continue;
            s += craw[yy * WW + xx];
        }
    }
    c2[i] = 0.5f * (craw[i] + s / 9.0f);
}

// ---------------- Kernel 3: 7x7 NMS + compact survivors ----------------
__global__ void k_nms(const float* __restrict__ c2, float* __restrict__ cand_val,
                      int* __restrict__ cand_idx, unsigned int* __restrict__ counter) {
    int i = blockIdx.x * blockDim.x + threadIdx.x;
    if (i >= NPIX) return;
    int x = i & (WW - 1);
    int y = i >> 9;
    float v = c2[i];
    float m = v;
    for (int dy = -3; dy <= 3; ++dy) {
        int yy = y + dy;
        if (yy < 0 || yy >= HH) continue;
        for (int dx = -3; dx <= 3; ++dx) {
            int xx = x + dx;
            if (xx < 0 || xx >= WW) continue;
            m = fmaxf(m, c2[yy * WW + xx]);
        }
    }
    if (v == m) {  // survivor (all heatmap values > 0, zeros from padding never win)
        unsigned int slot = atomicAdd(counter, 1u);
        if (slot < MAXC) {
            cand_val[slot] = v;
            cand_idx[slot] = i;
        }
    }
}

// ---------------- Kernel 4: top-30 selection + scalar outputs ----------------
// jax.lax.top_k: descending, ties -> lowest flat index first.
__global__ void k_topk(float* __restrict__ cand_val, const int* __restrict__ cand_idx,
                       const unsigned int* __restrict__ counter,
                       int* __restrict__ sel_out, float* __restrict__ out) {
    __shared__ float s_v[256];
    __shared__ int   s_i[256];
    __shared__ int   s_s[256];
    __shared__ float sel_v[NPROP];
    __shared__ int   sel_p[NPROP];
    int tid = threadIdx.x;
    int n = (int)min(*counter, (unsigned int)MAXC);

    for (int it = 0; it < NPROP; ++it) {
        float bv = -1.0f;        // all survivor values are > 0
        int   bi = 0x7fffffff;
        int   bs = -1;
        for (int s = tid; s < n; s += 256) {
            float v = cand_val[s];
            int   pi = cand_idx[s];
            if (v > bv || (v == bv && pi < bi)) { bv = v; bi = pi; bs = s; }
        }
        s_v[tid] = bv; s_i[tid] = bi; s_s[tid] = bs;
        __syncthreads();
        if (tid == 0) {
            float BV = -1.0f; int BI = 0x7fffffff; int BS = -1;
            for (int t = 0; t < 256; ++t) {
                if (s_v[t] > BV || (s_v[t] == BV && s_i[t] < BI)) {
                    BV = s_v[t]; BI = s_i[t]; BS = s_s[t];
                }
            }
            sel_v[it] = BV; sel_p[it] = BI;
            if (BS >= 0) cand_val[BS] = -2.0f;  // remove from future iterations
        }
        __syncthreads();
    }

    // outputs (all as float32):
    // [0,120)            instance_coord2  (60 rows of y,x)
    // [120,180)          instance_imgid
    // [180,180+15360)    instance_param   (written by gather kernel)
    // [15540,15600)      instance_score
    for (int r = tid; r < 60; r += 256) {
        int pi = sel_p[r % NPROP];
        out[r * 2 + 0] = (float)(pi >> 9);          // y
        out[r * 2 + 1] = (float)(pi & (WW - 1));    // x
        out[120 + r] = (r < NPROP) ? 0.0f : 1.0f;   // imgid
        out[180 + 15360 + r] = sel_v[r % NPROP];    // score
    }
    if (tid < NPROP) sel_out[tid] = sel_p[tid];
}

// ---------------- Kernel 5: feature gather -> instance_param [60,256] ----------------
__global__ void k_gather(const float* __restrict__ features, const int* __restrict__ sel,
                         float* __restrict__ out) {
    int r = blockIdx.x;    // 0..59
    int c = threadIdx.x;   // 0..255
    int pi = sel[r % NPROP];
    size_t b = (r < NPROP) ? 0 : 1;
    out[180 + r * 256 + c] = features[b * 256u * (size_t)NPIX + (size_t)c * NPIX + (size_t)pi];
}

extern "C" void kernel_launch(void* const* d_in, const int* in_sizes, int n_in,
                              void* d_out, int out_size, void* d_ws, size_t ws_size,
                              hipStream_t stream) {
    const float* features = (const float*)d_in[0];   // (2,256,512,512)
    const float* pred     = (const float*)d_in[1];   // (2,18,512,512)
    float* out = (float*)d_out;                      // 15600 floats

    char* w = (char*)d_ws;
    unsigned int* counter = (unsigned int*)w;                      // 4 B
    int*   sel      = (int*)(w + 128);                             // 30 ints
    float* craw     = (float*)(w + 1024);                          // 1 MiB
    float* c2       = (float*)(w + 1024 + (size_t)NPIX * 4);       // 1 MiB
    float* cand_val = (float*)(w + 1024 + (size_t)NPIX * 8);       // 128 KiB
    int*   cand_idx = (int*)  (w + 1024 + (size_t)NPIX * 8 + (size_t)MAXC * 4); // 128 KiB

    dim3 blk(256);
    dim3 grd(NPIX / 256);

    k_center_raw<<<grd, blk, 0, stream>>>(pred, craw, counter);
    k_center2<<<grd, blk, 0, stream>>>(craw, c2);
    k_nms<<<grd, blk, 0, stream>>>(c2, cand_val, cand_idx, counter);
    k_topk<<<1, blk, 0, stream>>>(cand_val, cand_idx, counter, sel, out);
    k_gather<<<60, blk, 0, stream>>>(features, sel, out);
}

// Round 2
// 112.147 us; speedup vs baseline: 7.9012x; 7.9012x over previous
//
#include <hip/hip_runtime.h>

#define HH 512
#define WW 512
#define NPIX (HH * WW)
#define NPROP 30
#define MAXC 32768
#define LDSN 7680   // 60 KB LDS staging for candidates

typedef unsigned long long u64;
typedef unsigned int u32;

// ---------------- Kernel 1: center_raw = mean over batch of channel 17 ----------------
__global__ void k_center_raw(const float* __restrict__ pred, float* __restrict__ craw,
                             u32* __restrict__ counter) {
    int i = blockIdx.x * blockDim.x + threadIdx.x;
    if (i == 0) *counter = 0u;  // reset candidate counter each call
    if (i < NPIX) {
        float a = pred[17 * NPIX + i];            // batch 0, channel 17
        float b = pred[(18 + 17) * NPIX + i];     // batch 1, channel 17
        craw[i] = 0.5f * (a + b);
    }
}

// ---------------- Kernel 2: center2 = (craw + avgpool3(craw)) / 2 ----------------
__global__ void k_center2(const float* __restrict__ craw, float* __restrict__ c2) {
    int i = blockIdx.x * blockDim.x + threadIdx.x;
    if (i >= NPIX) return;
    int x = i & (WW - 1);
    int y = i >> 9;
    float s = 0.0f;
    #pragma unroll
    for (int dy = -1; dy <= 1; ++dy) {
        int yy = y + dy;
        if (yy < 0 || yy >= HH) continue;
        #pragma unroll
        for (int dx = -1; dx <= 1; ++dx) {
            int xx = x + dx;
            if (xx < 0 || xx >= WW) continue;
            s += craw[yy * WW + xx];
        }
    }
    c2[i] = 0.5f * (craw[i] + s / 9.0f);
}

// ---------------- Kernel 3: 7x7 NMS + compact survivors as packed u64 keys ----------------
// key = (float_bits(v) << 32) | (NPIX-1-idx): max-key order == top_k order (ties -> lower idx)
__global__ void k_nms(const float* __restrict__ c2, u64* __restrict__ cand,
                      u32* __restrict__ counter) {
    int i = blockIdx.x * blockDim.x + threadIdx.x;
    if (i >= NPIX) return;
    int x = i & (WW - 1);
    int y = i >> 9;
    float v = c2[i];
    float m = v;
    for (int dy = -3; dy <= 3; ++dy) {
        int yy = y + dy;
        if (yy < 0 || yy >= HH) continue;
        for (int dx = -3; dx <= 3; ++dx) {
            int xx = x + dx;
            if (xx < 0 || xx >= WW) continue;
            m = fmaxf(m, c2[yy * WW + xx]);
        }
    }
    if (v == m) {  // survivor (heatmap values > 0)
        u32 slot = atomicAdd(counter, 1u);
        if (slot < MAXC) {
            cand[slot] = ((u64)__float_as_uint(v) << 32) | (u32)(NPIX - 1 - i);
        }
    }
}

// ---------------- Kernel 4: parallel top-30 extraction ----------------
__global__ __launch_bounds__(256) void k_topk(u64* __restrict__ cand,
                                              const u32* __restrict__ counter,
                                              int* __restrict__ sel_out,
                                              float* __restrict__ out) {
    __shared__ u64 lds[LDSN];
    __shared__ u64 wbest[4];
    __shared__ u64 bestk;
    __shared__ u64 selk[NPROP];
    int tid = threadIdx.x;
    int n = (int)min(*counter, (u32)MAXC);
    int nl = min(n, LDSN);

    for (int s = tid; s < nl; s += 256) lds[s] = cand[s];
    __syncthreads();

    for (int it = 0; it < NPROP; ++it) {
        u64 bk = 0; int bs = -1;
        for (int s = tid; s < nl; s += 256) {
            u64 k = lds[s];
            if (k > bk) { bk = k; bs = s; }
        }
        for (int s = LDSN + tid; s < n; s += 256) {   // overflow tail (normally empty)
            u64 k = cand[s];
            if (k > bk) { bk = k; bs = s; }
        }
        u64 rk = bk;
        #pragma unroll
        for (int off = 32; off > 0; off >>= 1) {
            u64 o = __shfl_xor(rk, off, 64);
            rk = (o > rk) ? o : rk;
        }
        if ((tid & 63) == 0) wbest[tid >> 6] = rk;
        __syncthreads();
        if (tid == 0) {
            u64 B = wbest[0];
            if (wbest[1] > B) B = wbest[1];
            if (wbest[2] > B) B = wbest[2];
            if (wbest[3] > B) B = wbest[3];
            bestk = B; selk[it] = B;
        }
        __syncthreads();
        u64 B = bestk;
        if (bs >= 0 && bk == B) {   // keys unique -> exactly one thread clears the winner
            if (bs < nl) lds[bs] = 0ull;
            else cand[bs] = 0ull;
        }
        __syncthreads();
    }

    // outputs (all float32):
    // [0,120) coords (60 x {y,x}), [120,180) imgid, [180,15540) params, [15540,15600) scores
    for (int r = tid; r < 60; r += 256) {
        u64 k = selk[r % NPROP];
        int pi = NPIX - 1 - (int)(k & 0xFFFFFFFFu);
        out[r * 2 + 0] = (float)(pi >> 9);          // y
        out[r * 2 + 1] = (float)(pi & (WW - 1));    // x
        out[120 + r] = (r < NPROP) ? 0.0f : 1.0f;   // imgid
        out[180 + 15360 + r] = __uint_as_float((u32)(k >> 32));  // score
    }
    if (tid < NPROP) sel_out[tid] = NPIX - 1 - (int)(selk[tid] & 0xFFFFFFFFu);
}

// ---------------- Kernel 5: feature gather -> instance_param [60,256] ----------------
__global__ void k_gather(const float* __restrict__ features, const int* __restrict__ sel,
                         float* __restrict__ out) {
    int r = blockIdx.x;    // 0..59
    int c = threadIdx.x;   // 0..255
    int pi = sel[r % NPROP];
    size_t b = (r < NPROP) ? 0 : 1;
    out[180 + r * 256 + c] = features[b * 256u * (size_t)NPIX + (size_t)c * NPIX + (size_t)pi];
}

extern "C" void kernel_launch(void* const* d_in, const int* in_sizes, int n_in,
                              void* d_out, int out_size, void* d_ws, size_t ws_size,
                              hipStream_t stream) {
    const float* features = (const float*)d_in[0];   // (2,256,512,512)
    const float* pred     = (const float*)d_in[1];   // (2,18,512,512)
    float* out = (float*)d_out;                      // 15600 floats

    char* w = (char*)d_ws;
    u32*   counter  = (u32*)w;                                     // 4 B
    int*   sel      = (int*)(w + 128);                             // 30 ints
    float* craw     = (float*)(w + 1024);                          // 1 MiB
    float* c2       = (float*)(w + 1024 + (size_t)NPIX * 4);       // 1 MiB
    u64*   cand     = (u64*)(w + 1024 + (size_t)NPIX * 8);         // 256 KiB

    dim3 blk(256);
    dim3 grd(NPIX / 256);

    k_center_raw<<<grd, blk, 0, stream>>>(pred, craw, counter);
    k_center2<<<grd, blk, 0, stream>>>(craw, c2);
    k_nms<<<grd, blk, 0, stream>>>(c2, cand, counter);
    k_topk<<<1, blk, 0, stream>>>(cand, counter, sel, out);
    k_gather<<<60, blk, 0, stream>>>(features, sel, out);
}

// Round 3
// 75.452 us; speedup vs baseline: 11.7438x; 1.4863x over previous
//
#include <hip/hip_runtime.h>

#define HH 512
#define WW 512
#define NPIX (HH * WW)
#define NPROP 30
#define MAXC 32768
#define LDSN 7680     // 60 KB LDS staging for candidates in topk
#define TILE 32
#define CR 40         // craw tile: TILE + 2*4 halo
#define C2R 38        // c2 tile:   TILE + 2*3 halo

typedef unsigned long long u64;
typedef unsigned int u32;

// ---------- Kernel 1 (fused): center mean + avgpool smooth + 7x7 NMS + compact ----------
// key = (float_bits(v) << 32) | (NPIX-1-idx): max-key order == top_k order (ties -> lower idx)
__global__ __launch_bounds__(256) void k_fused(const float* __restrict__ pred,
                                               u64* __restrict__ cand,
                                               u32* __restrict__ counter) {
    __shared__ float craw[CR * CR];
    __shared__ float c2[C2R * C2R];
    __shared__ float rm[C2R * TILE];
    __shared__ u64 skeys[96];          // max survivors per 32x32 tile of 7x7 NMS: 9x9=81
    __shared__ u32 scnt;
    __shared__ u32 sbase;
    int tid = threadIdx.x;
    int bx = blockIdx.x & 15, by = blockIdx.x >> 4;
    int ox = bx * TILE, oy = by * TILE;
    if (tid == 0) scnt = 0u;

    // stage craw = 0.5*(pred[b0,ch17] + pred[b1,ch17]), zero outside image
    for (int s = tid; s < CR * CR; s += 256) {
        int ly = s / CR, lx = s - ly * CR;
        int gy = oy - 4 + ly, gx = ox - 4 + lx;
        float v = 0.0f;
        if ((unsigned)gy < HH && (unsigned)gx < WW) {
            int g = gy * WW + gx;
            v = 0.5f * (pred[17 * NPIX + g] + pred[35 * NPIX + g]);
        }
        craw[s] = v;
    }
    __syncthreads();

    // c2 = 0.5*(craw + avgpool3(craw)/1)  (count_include_pad: always /9, zero-padded)
    for (int s = tid; s < C2R * C2R; s += 256) {
        int cy = s / C2R, cx = s - cy * C2R;
        int gy = oy - 3 + cy, gx = ox - 3 + cx;
        float v = 0.0f;
        if ((unsigned)gy < HH && (unsigned)gx < WW) {
            float sum = 0.0f;
            #pragma unroll
            for (int dy = 0; dy < 3; ++dy)
                #pragma unroll
                for (int dx = 0; dx < 3; ++dx)
                    sum += craw[(cy + dy) * CR + (cx + dx)];
            v = 0.5f * (craw[(cy + 1) * CR + (cx + 1)] + sum * (1.0f / 9.0f));
        }
        c2[s] = v;   // 0 outside image: never wins a max vs positive in-image values
    }
    __syncthreads();

    // separable 7x7 max, pass 1: row max over dx
    for (int s = tid; s < C2R * TILE; s += 256) {
        int ry = s >> 5, rx = s & 31;
        float m = c2[ry * C2R + rx];
        #pragma unroll
        for (int d = 1; d < 7; ++d) m = fmaxf(m, c2[ry * C2R + rx + d]);
        rm[s] = m;
    }
    __syncthreads();

    // pass 2: col max + peak test + per-block compaction
    for (int s = tid; s < TILE * TILE; s += 256) {
        int py = s >> 5, px = s & 31;
        float m = rm[py * TILE + px];
        #pragma unroll
        for (int d = 1; d < 7; ++d) m = fmaxf(m, rm[(py + d) * TILE + px]);
        float v = c2[(py + 3) * C2R + (px + 3)];
        if (v == m) {
            int gi = (oy + py) * WW + (ox + px);
            u32 slot = atomicAdd(&scnt, 1u);
            if (slot < 96u) skeys[slot] = ((u64)__float_as_uint(v) << 32) | (u32)(NPIX - 1 - gi);
        }
    }
    __syncthreads();
    u32 cnt = min(scnt, 96u);
    if (tid == 0) sbase = atomicAdd(counter, cnt);
    __syncthreads();
    for (u32 j = tid; j < cnt; j += 256) {
        u32 p = sbase + j;
        if (p < MAXC) cand[p] = skeys[j];
    }
}

// ---------- Kernel 2: top-30 via incremental tournament ----------
__global__ __launch_bounds__(256) void k_topk(u64* __restrict__ cand,
                                              const u32* __restrict__ counter,
                                              int* __restrict__ sel_out,
                                              float* __restrict__ out) {
    __shared__ u64 lds[LDSN];
    __shared__ u64 s_key[256];
    __shared__ u64 s_best;
    __shared__ u64 selk[NPROP];
    int tid = threadIdx.x;
    int n = (int)min(*counter, (u32)MAXC);
    int nl = min(n, LDSN);

    for (int s = tid; s < nl; s += 256) lds[s] = cand[s];
    __syncthreads();

    // per-thread stripe max (cached)
    u64 bk = 0ull; int bs = -1;
    for (int s = tid; s < nl; s += 256) { u64 k = lds[s]; if (k > bk) { bk = k; bs = s; } }
    for (int s = LDSN + tid; s < n; s += 256) { u64 k = cand[s]; if (k > bk) { bk = k; bs = s; } }
    s_key[tid] = bk;
    __syncthreads();

    for (int it = 0; it < NPROP; ++it) {
        if (tid < 64) {
            u64 m = s_key[tid];
            u64 b = s_key[tid + 64];  if (b > m) m = b;
            b = s_key[tid + 128];     if (b > m) m = b;
            b = s_key[tid + 192];     if (b > m) m = b;
            #pragma unroll
            for (int off = 32; off > 0; off >>= 1) {
                u64 o = __shfl_xor(m, off, 64);
                if (o > m) m = o;
            }
            if (tid == 0) { s_best = m; selk[it] = m; }
        }
        __syncthreads();
        u64 B = s_best;
        if (bk == B && bk != 0ull) {     // unique winner rescans its stripe only
            if (bs < LDSN) lds[bs] = 0ull; else cand[bs] = 0ull;
            bk = 0ull; bs = -1;
            for (int s = tid; s < nl; s += 256) { u64 k = lds[s]; if (k > bk) { bk = k; bs = s; } }
            for (int s = LDSN + tid; s < n; s += 256) { u64 k = cand[s]; if (k > bk) { bk = k; bs = s; } }
            s_key[tid] = bk;
        }
        __syncthreads();
    }

    // outputs (all float32):
    // [0,120) coords (60 x {y,x}), [120,180) imgid, [180,15540) params, [15540,15600) scores
    for (int r = tid; r < 60; r += 256) {
        u64 k = selk[r % NPROP];
        int pi = NPIX - 1 - (int)(k & 0xFFFFFFFFu);
        out[r * 2 + 0] = (float)(pi >> 9);          // y
        out[r * 2 + 1] = (float)(pi & (WW - 1));    // x
        out[120 + r] = (r < NPROP) ? 0.0f : 1.0f;   // imgid
        out[180 + 15360 + r] = __uint_as_float((u32)(k >> 32));  // score
    }
    if (tid < NPROP) sel_out[tid] = NPIX - 1 - (int)(selk[tid] & 0xFFFFFFFFu);
}

// ---------- Kernel 3: feature gather -> instance_param [60,256] ----------
__global__ void k_gather(const float* __restrict__ features, const int* __restrict__ sel,
                         float* __restrict__ out) {
    int r = blockIdx.x;    // 0..59
    int c = threadIdx.x;   // 0..255
    int pi = sel[r % NPROP];
    size_t b = (r < NPROP) ? 0 : 1;
    out[180 + r * 256 + c] = features[b * 256u * (size_t)NPIX + (size_t)c * NPIX + (size_t)pi];
}

extern "C" void kernel_launch(void* const* d_in, const int* in_sizes, int n_in,
                              void* d_out, int out_size, void* d_ws, size_t ws_size,
                              hipStream_t stream) {
    const float* features = (const float*)d_in[0];   // (2,256,512,512)
    const float* pred     = (const float*)d_in[1];   // (2,18,512,512)
    float* out = (float*)d_out;                      // 15600 floats

    char* w = (char*)d_ws;
    u32* counter = (u32*)w;                 // 4 B
    int* sel     = (int*)(w + 128);         // 30 ints
    u64* cand    = (u64*)(w + 1024);        // 256 KiB

    hipMemsetAsync(counter, 0, sizeof(u32), stream);
    k_fused<<<256, 256, 0, stream>>>(pred, cand, counter);
    k_topk<<<1, 256, 0, stream>>>(cand, counter, sel, out);
    k_gather<<<60, 256, 0, stream>>>(features, sel, out);
}

// Round 4
// 43.158 us; speedup vs baseline: 20.5317x; 1.7483x over previous
//
#include <hip/hip_runtime.h>

#define HH 512
#define WW 512
#define NPIX (HH * WW)
#define NPROP 30
#define REGC 96       // per-block candidate region capacity (hard max survivors/tile = 64)
#define TILE 32
#define CR 40         // craw tile: TILE + 2*4 halo
#define C2R 38        // c2 tile:   TILE + 2*3 halo

typedef unsigned long long u64;
typedef unsigned int u32;

// ---------- Kernel 1 (fused): center mean + avgpool smooth + 7x7 NMS + per-block compact ----------
// key = (float_bits(v) << 32) | (NPIX-1-idx): max-key order == top_k order (ties -> lower idx)
__global__ __launch_bounds__(256) void k_fused(const float* __restrict__ pred,
                                               u64* __restrict__ cand,
                                               u32* __restrict__ cnt) {
    __shared__ float craw[CR * CR];
    __shared__ float c2[C2R * C2R];
    __shared__ float rm[C2R * TILE];
    __shared__ u64 skeys[REGC];
    __shared__ u32 scnt;
    int tid = threadIdx.x;
    int bx = blockIdx.x & 15, by = blockIdx.x >> 4;
    int ox = bx * TILE, oy = by * TILE;
    if (tid == 0) scnt = 0u;

    // stage craw = 0.5*(pred[b0,ch17] + pred[b1,ch17]), zero outside image
    for (int s = tid; s < CR * CR; s += 256) {
        int ly = s / CR, lx = s - ly * CR;
        int gy = oy - 4 + ly, gx = ox - 4 + lx;
        float v = 0.0f;
        if ((unsigned)gy < HH && (unsigned)gx < WW) {
            int g = gy * WW + gx;
            v = 0.5f * (pred[17 * NPIX + g] + pred[35 * NPIX + g]);
        }
        craw[s] = v;
    }
    __syncthreads();

    // c2 = 0.5*(craw + avgpool3(craw))  (count_include_pad: always /9, zero-padded)
    for (int s = tid; s < C2R * C2R; s += 256) {
        int cy = s / C2R, cx = s - cy * C2R;
        int gy = oy - 3 + cy, gx = ox - 3 + cx;
        float v = 0.0f;
        if ((unsigned)gy < HH && (unsigned)gx < WW) {
            float sum = 0.0f;
            #pragma unroll
            for (int dy = 0; dy < 3; ++dy)
                #pragma unroll
                for (int dx = 0; dx < 3; ++dx)
                    sum += craw[(cy + dy) * CR + (cx + dx)];
            v = 0.5f * (craw[(cy + 1) * CR + (cx + 1)] + sum * (1.0f / 9.0f));
        }
        c2[s] = v;   // 0 outside image never wins vs positive in-image values
    }
    __syncthreads();

    // separable 7x7 max, pass 1: row max
    for (int s = tid; s < C2R * TILE; s += 256) {
        int ry = s >> 5, rx = s & 31;
        float m = c2[ry * C2R + rx];
        #pragma unroll
        for (int d = 1; d < 7; ++d) m = fmaxf(m, c2[ry * C2R + rx + d]);
        rm[s] = m;
    }
    __syncthreads();

    // pass 2: col max + peak test + per-block compaction in LDS
    for (int s = tid; s < TILE * TILE; s += 256) {
        int py = s >> 5, px = s & 31;
        float m = rm[py * TILE + px];
        #pragma unroll
        for (int d = 1; d < 7; ++d) m = fmaxf(m, rm[(py + d) * TILE + px]);
        float v = c2[(py + 3) * C2R + (px + 3)];
        if (v == m) {
            int gi = (oy + py) * WW + (ox + px);
            u32 slot = atomicAdd(&scnt, 1u);
            if (slot < REGC) skeys[slot] = ((u64)__float_as_uint(v) << 32) | (u32)(NPIX - 1 - gi);
        }
    }
    __syncthreads();
    u32 c = min(scnt, (u32)REGC);
    for (u32 j = tid; j < c; j += 256) cand[(size_t)blockIdx.x * REGC + j] = skeys[j];
    if (tid == 0) cnt[blockIdx.x] = c;
}

// ---------- Kernel 2: single-wave barrier-free top-30 ----------
__global__ __launch_bounds__(64) void k_topk(const u64* __restrict__ cand,
                                             const u32* __restrict__ cnt,
                                             int* __restrict__ sel_out,
                                             float* __restrict__ out) {
    int lane = threadIdx.x;
    // initial scan: 4 regions per lane -> top-4 in registers (static-indexed)
    u64 t0 = 0, t1 = 0, t2 = 0, t3 = 0;
    int nvalid = 0;
    #pragma unroll
    for (int rr = 0; rr < 4; ++rr) {
        int reg = lane * 4 + rr;
        u32 c = cnt[reg];
        const u64* p = cand + (size_t)reg * REGC;
        for (u32 j = 0; j < c; ++j) {
            u64 k = p[j];
            if (k > t3) {
                if (k > t0)      { t3 = t2; t2 = t1; t1 = t0; t0 = k; }
                else if (k > t1) { t3 = t2; t2 = t1; t1 = k; }
                else if (k > t2) { t3 = t2; t2 = k; }
                else               t3 = k;
            }
        }
        nvalid += (int)c;
    }

    int pops = 0;
    u64 mykey = 0;
    for (int it = 0; it < NPROP; ++it) {
        u64 m = t0;
        #pragma unroll
        for (int off = 32; off > 0; off >>= 1) {
            u64 o = __shfl_xor(m, off, 64);
            if (o > m) m = o;
        }
        if (lane % NPROP == it) mykey = m;   // lanes it and it+30 capture winner it
        if (t0 == m && m != 0ull) {          // unique winner lane pops its list
            t0 = t1; t1 = t2; t2 = t3; t3 = 0;
            ++pops;
            u64 thr = m;                      // popped keys are exactly those >= thr
            if (t0 == 0ull && pops < nvalid) {
                // rare refill: rebuild top-4 among remaining (< thr) from global
                #pragma unroll
                for (int rr = 0; rr < 4; ++rr) {
                    int reg = lane * 4 + rr;
                    u32 c = cnt[reg];
                    const u64* p = cand + (size_t)reg * REGC;
                    for (u32 j = 0; j < c; ++j) {
                        u64 k = p[j];
                        if (k < thr && k > t3) {
                            if (k > t0)      { t3 = t2; t2 = t1; t1 = t0; t0 = k; }
                            else if (k > t1) { t3 = t2; t2 = t1; t1 = k; }
                            else if (k > t2) { t3 = t2; t2 = k; }
                            else               t3 = k;
                        }
                    }
                }
            }
        }
    }

    // outputs (all float32):
    // [0,120) coords (60 x {y,x}), [120,180) imgid, [180,15540) params, [15540,15600) scores
    if (lane < 60) {
        int pi = NPIX - 1 - (int)(mykey & 0xFFFFFFFFu);
        out[lane * 2 + 0] = (float)(pi >> 9);          // y
        out[lane * 2 + 1] = (float)(pi & (WW - 1));    // x
        out[120 + lane] = (lane < NPROP) ? 0.0f : 1.0f;
        out[180 + 15360 + lane] = __uint_as_float((u32)(mykey >> 32));
        if (lane < NPROP) sel_out[lane] = pi;
    }
}

// ---------- Kernel 3: feature gather -> instance_param [60,256] ----------
__global__ void k_gather(const float* __restrict__ features, const int* __restrict__ sel,
                         float* __restrict__ out) {
    int r = blockIdx.x;    // 0..59
    int c = threadIdx.x;   // 0..255
    int pi = sel[r % NPROP];
    size_t b = (r < NPROP) ? 0 : 1;
    out[180 + r * 256 + c] = features[b * 256u * (size_t)NPIX + (size_t)c * NPIX + (size_t)pi];
}

extern "C" void kernel_launch(void* const* d_in, const int* in_sizes, int n_in,
                              void* d_out, int out_size, void* d_ws, size_t ws_size,
                              hipStream_t stream) {
    const float* features = (const float*)d_in[0];   // (2,256,512,512)
    const float* pred     = (const float*)d_in[1];   // (2,18,512,512)
    float* out = (float*)d_out;                      // 15600 floats

    char* w = (char*)d_ws;
    int* sel = (int*)w;                    // 120 B
    u32* cnt = (u32*)(w + 512);            // 1 KiB
    u64* cand = (u64*)(w + 2048);          // 192 KiB

    k_fused<<<256, 256, 0, stream>>>(pred, cand, cnt);
    k_topk<<<1, 64, 0, stream>>>(cand, cnt, sel, out);
    k_gather<<<60, 256, 0, stream>>>(features, sel, out);
}